// Round 17
// baseline (135.937 us; speedup 1.0000x reference)
//
#include <hip/hip_runtime.h>
#include <math.h>

using bfrag8 = __attribute__((ext_vector_type(8))) short;
using facc4  = __attribute__((ext_vector_type(4))) float;

#define MFMA16(a,b,c) __builtin_amdgcn_mfma_f32_16x16x32_bf16((a),(b),(c),0,0,0)

#define T_SEQ 827
#define T_PAD 832
#define NHEAD 16
#define NEG_INF (-__builtin_inff())
#define CM_TOT 1179392   // 4*542*544

static __device__ __forceinline__ unsigned short f2bf(float f) {
    unsigned int x = __float_as_uint(f);
    unsigned int r = x + 0x7FFFu + ((x >> 16) & 1u);
    return (unsigned short)(r >> 16);
}

// global -> LDS async copy, 16B per lane. LDS dest must be wave-uniform base (+lane*16 auto).
static __device__ __forceinline__ void gl16(const void* g, void* l) {
    __builtin_amdgcn_global_load_lds(
        (const __attribute__((address_space(1))) unsigned int*)g,
        (__attribute__((address_space(3))) unsigned int*)l,
        16, 0, 0);
}

// ---------------- fused front: x->bf16 | cm:=1 | qkv pads | W transpose | blur ----
__global__ __launch_bounds__(256) void k_front(const float* __restrict__ x,
                                               unsigned short* __restrict__ x_bf,
                                               float* __restrict__ cm,
                                               unsigned short* q, unsigned short* k,
                                               unsigned short* vT,
                                               const float* __restrict__ Wq,
                                               const float* __restrict__ Wk,
                                               const float* __restrict__ Wv,
                                               const float* __restrict__ Wp,
                                               unsigned short* __restrict__ Wt_out,
                                               const float* f01, const float* f02, const float* f12,
                                               const float* b01, const float* b02, const float* b12,
                                               float* __restrict__ bl,
                                               float* __restrict__ pmm) {
    __shared__ float tile[32][33];
    __shared__ float img[16][17], tmp[16][17];
    __shared__ float smn[4], smx[4];
    int bid = blockIdx.x, tid = threadIdx.x;

    if (bid < 3308) {
        int i = (bid * 256 + tid) * 4;
        float4 v = *reinterpret_cast<const float4*>(x + i);
        ushort4 o;
        o.x = f2bf(v.x); o.y = f2bf(v.y); o.z = f2bf(v.z); o.w = f2bf(v.w);
        *reinterpret_cast<ushort4*>(x_bf + i) = o;
    } else if (bid < 4460) {
        int base = (bid - 3308) * 1024 + tid * 4;
        if (base + 4 <= CM_TOT) {
            float4 one = {1.f, 1.f, 1.f, 1.f};
            *reinterpret_cast<float4*>(cm + base) = one;
        } else {
#pragma unroll
            for (int j = 0; j < 4; ++j)
                if (base + j < CM_TOT) cm[base + j] = 1.f;
        }
    } else if (bid < 4524) {
        int bh = bid - 4460;
        for (int i = tid; i < 320; i += 256) {
            int t = 827 + i / 64, d = i % 64;
            q[((size_t)bh * T_PAD + t) * 64 + d] = 0;
            k[((size_t)bh * T_PAD + t) * 64 + d] = 0;
        }
        for (int i = tid; i < 4096; i += 256) {
            int d = i >> 6, s = 768 + (i & 63);
            vT[((size_t)bh * 64 + d) * T_PAD + s] = 0;
        }
    } else if (bid < 8620) {
        int i = bid - 4524;
        int z = i >> 10, rem = i & 1023;
        int bx = rem & 31, by = rem >> 5;
        const float* W = (z == 0) ? Wq : (z == 1) ? Wk : (z == 2) ? Wv : Wp;
        unsigned short* Wt = Wt_out + (size_t)z * 1048576;
        int tx = tid & 31, ty0 = tid >> 5;
#pragma unroll
        for (int j = 0; j < 4; ++j) {
            int ty = ty0 + j * 8;
            tile[ty][tx] = W[(size_t)(by * 32 + ty) * 1024 + bx * 32 + tx];
        }
        __syncthreads();
#pragma unroll
        for (int j = 0; j < 4; ++j) {
            int ty = ty0 + j * 8;
            Wt[(size_t)(bx * 32 + ty) * 1024 + by * 32 + tx] = f2bf(tile[tx][ty]);
        }
    } else {
        int i = bid - 8620;
        int m = i >> 10, rem = i & 1023, b = rem >> 8, r = rem & 255;
        const float* f  = (m == 0) ? f01 : (m == 1) ? f02 : f12;
        const float* bm = (m == 0) ? b01 : (m == 1) ? b02 : b12;
        int ii = tid >> 4, j = tid & 15;

        float k1[7]; float ks = 0.f;
#pragma unroll
        for (int d = 0; d < 7; ++d) { float hx = (float)d - 3.f; k1[d] = expf(-0.5f * hx * hx / 2.25f); ks += k1[d]; }
#pragma unroll
        for (int d = 0; d < 7; ++d) k1[d] /= ks;

        size_t idx = (size_t)b * 65536 + (size_t)r * 256 + tid;
        float bi = f[idx] * bm[(size_t)b * 65536 + (size_t)tid * 256 + r];
        img[ii][j] = bi;
        __syncthreads();
        float ha = 0.f;
#pragma unroll
        for (int d = 0; d < 7; ++d) { int p = j - 3 + d; p = p < 0 ? -p : (p > 15 ? 30 - p : p); ha += k1[d] * img[ii][p]; }
        tmp[ii][j] = ha;
        __syncthreads();
        float v = 0.f;
#pragma unroll
        for (int d = 0; d < 7; ++d) { int p = ii - 3 + d; p = p < 0 ? -p : (p > 15 ? 30 - p : p); v += k1[d] * tmp[p][j]; }
        bl[(size_t)m * 262144 + idx] = v;

        float mn = v, mx = v;
#pragma unroll
        for (int off = 32; off; off >>= 1) { mn = fminf(mn, __shfl_xor(mn, off)); mx = fmaxf(mx, __shfl_xor(mx, off)); }
        int wid = tid >> 6, lane = tid & 63;
        if (lane == 0) { smn[wid] = mn; smx[wid] = mx; }
        __syncthreads();
        if (tid == 0) {
            mn = fminf(fminf(smn[0], smn[1]), fminf(smn[2], smn[3]));
            mx = fmaxf(fmaxf(smx[0], smx[1]), fmaxf(smx[2], smx[3]));
            pmm[2 * i]     = mn;    // plain stores, no atomics
            pmm[2 * i + 1] = mx;
        }
    }
}

// ---------------- QKV GEMM 128x128, dbuf LDS + counted vmcnt + finalize tail ------
__global__ __launch_bounds__(256) void k_gemm_qkv(const unsigned short* __restrict__ A,
                                              const unsigned short* __restrict__ Bt,
                                              const float* __restrict__ b0, const float* __restrict__ b1,
                                              const float* __restrict__ b2,
                                              unsigned short* __restrict__ qo, unsigned short* __restrict__ ko,
                                              unsigned short* __restrict__ vo, int M,
                                              const float* f01, const float* f02, const float* f12,
                                              const float* b01, const float* b02, const float* b12,
                                              const float* __restrict__ bl,
                                              const float* __restrict__ pmm,
                                              float* __restrict__ cm) {
    __shared__ unsigned short As[2][4096];
    __shared__ unsigned short Bs[2][4096];
    int bid = blockIdx.x, tid = threadIdx.x;

    if (bid >= 624) {
        int i = bid - 624;
        int m = i >> 10, rem = i & 1023, b = rem >> 8, r = rem & 255;
        float mn = __builtin_inff(), mx = 0.f;
        for (int kk = tid; kk < 1024; kk += 256) {
            int e = m * 1024 + kk;
            mn = fminf(mn, pmm[2 * e]);
            mx = fmaxf(mx, pmm[2 * e + 1]);
        }
#pragma unroll
        for (int off = 32; off; off >>= 1) { mn = fminf(mn, __shfl_xor(mn, off)); mx = fmaxf(mx, __shfl_xor(mx, off)); }
        float* fs = reinterpret_cast<float*>(&As[0][0]);
        int wid = tid >> 6, lane = tid & 63;
        if (lane == 0) { fs[wid] = mn; fs[4 + wid] = mx; }
        __syncthreads();
        mn = fminf(fminf(fs[0], fs[1]), fminf(fs[2], fs[3]));
        mx = fmaxf(fmaxf(fs[4], fs[5]), fmaxf(fs[6], fs[7]));

        const float* f  = (m == 0) ? f01 : (m == 1) ? f02 : f12;
        const float* bm = (m == 0) ? b01 : (m == 1) ? b02 : b12;
        size_t idx = (size_t)b * 65536 + (size_t)r * 256 + tid;
        float w = (bl[(size_t)m * 262144 + idx] - mn) / (mx - mn);
        w = fminf(fmaxf(w, 0.f), 1.f);
        float val = w * f[idx] * bm[(size_t)b * 65536 + (size_t)tid * 256 + r];
        int row = (m == 0) ? r : r + 286;
        int col = (m == 2) ? tid + 286 : tid;
        cm[((size_t)b * 542 + row) * 544 + col] = val;
        return;
    }

    int swz = (bid & 7) * 78 + (bid >> 3);   // 624 = 8*78
    int m0 = (swz % 26) * 128, n0 = (swz / 26) * 128;
    int wid = tid >> 6, lane = tid & 63;
    int g = lane >> 4, l15 = lane & 15;
    int wm = wid >> 1, wn = wid & 1;
    facc4 acc[4][4] = {};

    int ar0 = m0 + (tid >> 2); if (ar0 > M - 1) ar0 = M - 1;
    int ar1 = m0 + 64 + (tid >> 2); if (ar1 > M - 1) ar1 = M - 1;
    const unsigned short* Ap0 = A + (size_t)ar0 * 1024 + (tid & 3) * 8;
    const unsigned short* Ap1 = A + (size_t)ar1 * 1024 + (tid & 3) * 8;
    const unsigned short* Bp0 = Bt + (size_t)(n0 + (tid >> 2)) * 1024 + (tid & 3) * 8;
    const unsigned short* Bp1 = Bp0 + (size_t)64 * 1024;

    auto stage = [&](int koff, int buf) {
        gl16(Ap0 + koff, &As[buf][0] + (wid << 9));
        gl16(Ap1 + koff, &As[buf][0] + (wid << 9) + 2048);
        gl16(Bp0 + koff, &Bs[buf][0] + (wid << 9));
        gl16(Bp1 + koff, &Bs[buf][0] + (wid << 9) + 2048);
    };

    stage(0, 0);
    for (int k0 = 0; k0 < 32; ++k0) {
        int cur = k0 & 1;
        bool morek = (k0 + 1 < 32);
        if (morek) {
            stage((k0 + 1) * 32, cur ^ 1);
            asm volatile("s_waitcnt vmcnt(4)" ::: "memory");
        } else {
            asm volatile("s_waitcnt vmcnt(0)" ::: "memory");
        }
        __builtin_amdgcn_s_barrier();
        __builtin_amdgcn_sched_barrier(0);

        bfrag8 af[4], bf[4];
#pragma unroll
        for (int mi = 0; mi < 4; ++mi)
            af[mi] = *reinterpret_cast<const bfrag8*>(&As[cur][(wm * 64 + mi * 16 + l15) * 32 + g * 8]);
#pragma unroll
        for (int ni = 0; ni < 4; ++ni)
            bf[ni] = *reinterpret_cast<const bfrag8*>(&Bs[cur][(wn * 64 + ni * 16 + l15) * 32 + g * 8]);
        __builtin_amdgcn_s_setprio(1);
#pragma unroll
        for (int mi = 0; mi < 4; ++mi)
#pragma unroll
            for (int ni = 0; ni < 4; ++ni)
                acc[mi][ni] = MFMA16(af[mi], bf[ni], acc[mi][ni]);
        __builtin_amdgcn_s_setprio(0);

        __builtin_amdgcn_sched_barrier(0);
        if (morek) __builtin_amdgcn_s_barrier();
    }

    int which = n0 >> 10;
    const float* bb = (which == 0 ? b0 : (which == 1 ? b1 : b2));
#pragma unroll
    for (int mi = 0; mi < 4; ++mi)
#pragma unroll
        for (int ni = 0; ni < 4; ++ni)
#pragma unroll
            for (int r = 0; r < 4; ++r) {
                int row = m0 + wm * 64 + mi * 16 + g * 4 + r;
                if (row >= M) continue;
                int col = n0 + wn * 64 + ni * 16 + l15;
                float v = acc[mi][ni][r] + bb[col & 1023];
                int b = row / T_SEQ, t = row - b * T_SEQ;
                int cc = col & 1023;
                int hh = cc >> 6, d = cc & 63;
                size_t bh = (size_t)(b * NHEAD + hh);
                if (which == 0) {
                    qo[(bh * T_PAD + t) * 64 + d] = f2bf(v);
                } else if (which == 1) {
                    int du = (((d >> 3) ^ (t & 7)) << 3) | (d & 7);
                    ko[(bh * T_PAD + t) * 64 + du] = f2bf(v);
                } else {
                    int sl = t & 63;
                    int su = (((sl >> 3) ^ (d & 7)) << 3) | (t & 7);
                    vo[(bh * 64 + d) * T_PAD + (t - sl) + su] = f2bf(v);
                }
            }
}

// ---------------- proj GEMM: 64x64 tile, 832 blocks = 3.25/CU ---------------------
__global__ __launch_bounds__(256) void k_proj64(const unsigned short* __restrict__ A,
                                                const unsigned short* __restrict__ Bt,
                                                const float* __restrict__ bias,
                                                float* __restrict__ out, int M) {
    __shared__ unsigned short As[2048];
    __shared__ unsigned short Bs[2048];
    int bid = blockIdx.x, tid = threadIdx.x;
    int swz = (bid & 7) * 104 + (bid >> 3);
    int m0 = (swz % 52) * 64, n0 = (swz / 52) * 64;
    int wid = tid >> 6, lane = tid & 63;
    int g = lane >> 4, l15 = lane & 15;
    int wm = wid >> 1, wn = wid & 1;
    facc4 acc[2][2] = {};

    int ar = m0 + (tid >> 2); if (ar > M - 1) ar = M - 1;
    const unsigned short* Ap = A + (size_t)ar * 1024 + (tid & 3) * 8;
    const unsigned short* Bp = Bt + (size_t)(n0 + (tid >> 2)) * 1024 + (tid & 3) * 8;
    unsigned short* asw = As + (wid << 9);
    unsigned short* bsw = Bs + (wid << 9);

    for (int k0 = 0; k0 < 1024; k0 += 32) {
        if (k0) __syncthreads();
        gl16(Ap + k0, asw);
        gl16(Bp + k0, bsw);
        __syncthreads();
        bfrag8 af[2], bf[2];
#pragma unroll
        for (int mi = 0; mi < 2; ++mi)
            af[mi] = *reinterpret_cast<const bfrag8*>(&As[(wm * 32 + mi * 16 + l15) * 32 + g * 8]);
#pragma unroll
        for (int ni = 0; ni < 2; ++ni)
            bf[ni] = *reinterpret_cast<const bfrag8*>(&Bs[(wn * 32 + ni * 16 + l15) * 32 + g * 8]);
#pragma unroll
        for (int mi = 0; mi < 2; ++mi)
#pragma unroll
            for (int ni = 0; ni < 2; ++ni)
                acc[mi][ni] = MFMA16(af[mi], bf[ni], acc[mi][ni]);
    }

#pragma unroll
    for (int mi = 0; mi < 2; ++mi)
#pragma unroll
        for (int ni = 0; ni < 2; ++ni)
#pragma unroll
            for (int r = 0; r < 4; ++r) {
                int row = m0 + wm * 32 + mi * 16 + g * 4 + r;
                if (row >= M) continue;
                int col = n0 + wn * 32 + ni * 16 + l15;
                out[(size_t)row * 1024 + col] = acc[mi][ni][r] + bias[col];
            }
}

// ---------------- flash attention v9: split-s load balancing ----------------------
// grid 1216 = 64 bh x 19 jobs. jobs 0..6: qt=j full range (direct y write).
// jobs 7..18: qt=7+(j-7)/2, half=(j-7)&1 -> write (m,l,acc) partials.
__global__ __launch_bounds__(256) void k_attn(const unsigned short* __restrict__ qb,
                                              const unsigned short* __restrict__ kb,
                                              const unsigned short* __restrict__ vT,
                                              const float* __restrict__ h,
                                              const float* __restrict__ cm,
                                              unsigned short* __restrict__ y,
                                              float* __restrict__ pacc,
                                              float* __restrict__ pml) {
    int blk0 = blockIdx.x;
    int swz = (blk0 & 7) * 152 + (blk0 >> 3);   // 1216 = 8*152, bijective
    int bh = swz / 19, j = swz % 19;
    int qt, itlo, ithi, pidx = -1;
    if (j < 7) {
        qt = j; itlo = 0; ithi = qt + 1;
    } else {
        qt = 7 + ((j - 7) >> 1);
        int half = (j - 7) & 1;
        int h0 = (qt + 2) >> 1;
        itlo = half ? h0 : 0;
        ithi = half ? (qt + 1) : h0;
        pidx = bh * 12 + (qt - 7) * 2 + half;
    }
    int b = bh >> 4, hh = bh & 15;
    int tid = threadIdx.x, wid = tid >> 6, lane = tid & 63;
    int g = lane >> 4, l15 = lane & 15;
    int t0 = qt * 64 + wid * 16;
    int t = t0 + l15;               // this lane's t-column
    int tcl = t > 826 ? 826 : t;

    __shared__ unsigned short Ks[2][4096];
    __shared__ unsigned short Vs[2][4096];
    __shared__ unsigned short Ps[4][1024];
    unsigned short* pw = &Ps[wid][0];

    const unsigned short* Kbase = kb + (size_t)bh * T_PAD * 64;
    const unsigned short* Vbase = vT + (size_t)bh * 64 * T_PAD;
    const float* hrow = h + (size_t)bh * T_SEQ * T_SEQ + (size_t)tcl * T_SEQ;
    int rt = t - 285; rt = rt < 0 ? 0 : (rt > 541 ? 541 : rt);
    const float* cmrow = cm + ((size_t)b * 542 + rt) * 544;
    bool tm = (t >= 285);

    // Q fragments (B-operand; lane l15 = t-column)
    size_t qrow = ((size_t)bh * T_PAD + t) * 64 + g * 8;
    bfrag8 aq0 = *reinterpret_cast<const bfrag8*>(qb + qrow);
    bfrag8 aq1 = *reinterpret_cast<const bfrag8*>(qb + qrow + 32);

    auto stage = [&](int s0, int buf) {
        const unsigned short* kt = Kbase + (size_t)s0 * 64;
        unsigned short* kd = &Ks[buf][0] + (wid << 9);
        gl16(kt + tid * 8, kd);
        gl16(kt + 2048 + tid * 8, kd + 2048);
        const unsigned short* vt = Vbase + s0;
        unsigned short* vd = &Vs[buf][0] + (wid << 9);
        gl16(vt + (size_t)(tid >> 3) * T_PAD + (tid & 7) * 8, vd);
        gl16(vt + (size_t)((tid >> 3) + 32) * T_PAD + (tid & 7) * 8, vd + 2048);
    };

    auto loadh = [&](int s0t, float* hv, float* mv) {
#pragma unroll
        for (int nt = 0; nt < 4; ++nt) {
            int sb = s0t + nt * 16 + 4 * g;
            float h4[4];
            if (sb + 3 <= tcl) {
                __builtin_memcpy(h4, hrow + sb, 16);
            } else {
#pragma unroll
                for (int jj = 0; jj < 4; ++jj) {
                    float hx = 0.f;
                    if (sb + jj <= tcl) hx = hrow[sb + jj];
                    h4[jj] = hx;
                }
            }
            float m4[4];
            if (tm && sb <= 540) {
                __builtin_memcpy(m4, cmrow + sb, 16);
            } else {
#pragma unroll
                for (int jj = 0; jj < 4; ++jj) m4[jj] = 1.f;
            }
#pragma unroll
            for (int jj = 0; jj < 4; ++jj) { hv[nt * 4 + jj] = h4[jj]; mv[nt * 4 + jj] = m4[jj]; }
        }
    };

    float m_r = NEG_INF, l_r = 0.f;
    facc4 acc[4] = {};
    float hv[16], mv[16];
    loadh(itlo * 64, hv, mv);
    stage(itlo * 64, 0);

    for (int it = itlo; it < ithi; ++it) {
        int cur = (it - itlo) & 1, s0 = it * 64;
        bool more = (it + 1 < ithi);
        bool diag = (it == qt);            // only the true diagonal tile masks
        __syncthreads();                   // stage(it) complete
        if (more) stage(s0 + 64, cur ^ 1);

        // ---- QK^T (swapped: A=K, B=Q) -> lane holds S[s=s0+nt*16+4g+r][t] ----
        facc4 sf[4] = {};
        __builtin_amdgcn_s_setprio(1);
#pragma unroll
        for (int nt = 0; nt < 4; ++nt) {
            int row = nt * 16 + l15;
            const unsigned short* kp = &Ks[cur][row * 64];
            bfrag8 k0 = *reinterpret_cast<const bfrag8*>(kp + ((g ^ (row & 7)) << 3));
            bfrag8 k1 = *reinterpret_cast<const bfrag8*>(kp + (((4 + g) ^ (row & 7)) << 3));
            sf[nt] = MFMA16(k0, aq0, sf[nt]);
            sf[nt] = MFMA16(k1, aq1, sf[nt]);
        }
        __builtin_amdgcn_s_setprio(0);

        // ---- score + in-register partial max ----
        float vmax = NEG_INF;
#pragma unroll
        for (int nt = 0; nt < 4; ++nt)
#pragma unroll
            for (int r = 0; r < 4; ++r) {
                float val = fmaf(sf[nt][r], 0.125f, hv[nt * 4 + r]) * mv[nt * 4 + r];
                if (diag) {
                    int s = s0 + nt * 16 + 4 * g + r;
                    val = (s <= tcl) ? val : NEG_INF;
                }
                sf[nt][r] = val;
                vmax = fmaxf(vmax, val);
            }

        if (more) loadh(s0 + 64, hv, mv);  // prefetch next tile's h/mask

        vmax = fmaxf(vmax, __shfl_xor(vmax, 16));
        vmax = fmaxf(vmax, __shfl_xor(vmax, 32));

        // ---- defer-max (T13): skip rescale when growth <= THR ----
        bool noresc = __all(vmax <= m_r + 6.0f);
        float mnew = fmaxf(m_r, vmax);
        float mexp = noresc ? m_r : mnew;

        float ps = 0.f;
#pragma unroll
        for (int nt = 0; nt < 4; ++nt)
#pragma unroll
            for (int r = 0; r < 4; ++r) {
                float p = __expf(sf[nt][r] - mexp);
                sf[nt][r] = p;
                ps += p;
            }
        ps += __shfl_xor(ps, 16);
        ps += __shfl_xor(ps, 32);

        // ---- pack P (bf16) -> LDS [t][s] swizzled ----
#pragma unroll
        for (int nt = 0; nt < 4; ++nt) {
            unsigned u0, u1;
            asm("v_cvt_pk_bf16_f32 %0, %1, %2" : "=v"(u0) : "v"(sf[nt][0]), "v"(sf[nt][1]));
            asm("v_cvt_pk_bf16_f32 %0, %1, %2" : "=v"(u1) : "v"(sf[nt][2]), "v"(sf[nt][3]));
            int el = (l15 * 64 + nt * 16 + 4 * g) ^ ((l15 & 7) << 3);
            uint2 uu; uu.x = u0; uu.y = u1;
            *reinterpret_cast<uint2*>(&pw[el]) = uu;
        }

        // ---- online-softmax state update ----
        if (!noresc) {
            float scale = __expf(m_r - mnew);
            l_r = l_r * scale + ps;
#pragma unroll
            for (int r = 0; r < 4; ++r) {
                float sc = __int_as_float(__builtin_amdgcn_ds_bpermute((4 * g + r) * 4, __float_as_int(scale)));
#pragma unroll
                for (int dt = 0; dt < 4; ++dt) acc[dt][r] *= sc;
            }
            m_r = mnew;
        } else {
            l_r += ps;
        }

        // ---- PV: A=P (LDS), B=V^T (LDS) ----
        __builtin_amdgcn_s_setprio(1);
#pragma unroll
        for (int c2 = 0; c2 < 2; ++c2) {
            int ela = (l15 * 64 + c2 * 32 + 8 * g) ^ ((l15 & 7) << 3);
            bfrag8 ap = *reinterpret_cast<const bfrag8*>(&pw[ela]);
#pragma unroll
            for (int dt = 0; dt < 4; ++dt) {
                int row = dt * 16 + l15;
                bfrag8 vf = *reinterpret_cast<const bfrag8*>(&Vs[cur][row * 64 + (((c2 * 4 + g) ^ (row & 7)) << 3)]);
                acc[dt] = MFMA16(ap, vf, acc[dt]);
            }
        }
        __builtin_amdgcn_s_setprio(0);
    }

    if (pidx < 0) {
        // ---- direct y write (single-chunk jobs) ----
        float linv = 1.0f / l_r;
#pragma unroll
        for (int r = 0; r < 4; ++r) {
            float li = __int_as_float(__builtin_amdgcn_ds_bpermute((4 * g + r) * 4, __float_as_int(linv)));
            int tt = t0 + 4 * g + r;
            if (tt < T_SEQ) {
#pragma unroll
                for (int dt = 0; dt < 4; ++dt)
                    y[((size_t)(b * T_SEQ) + tt) * 1024 + hh * 64 + dt * 16 + l15] = f2bf(acc[dt][r] * li);
            }
        }
    } else {
        // ---- partial write: m,l per t-column (row = wid*16 + l15), acc rows 4g+r --
        float* pa = pacc + (size_t)pidx * 4096;
        float* pm = pml + (size_t)pidx * 128;
        if (g == 0) {
            int prow = wid * 16 + l15;     // FIX: per-wave row index (was l15 only)
            pm[prow * 2]     = m_r;
            pm[prow * 2 + 1] = l_r;
        }
#pragma unroll
        for (int dt = 0; dt < 4; ++dt)
#pragma unroll
            for (int r = 0; r < 4; ++r)
                pa[(wid * 16 + 4 * g + r) * 64 + dt * 16 + l15] = acc[dt][r];
    }
}

// ---------------- combine: merge 2 partials per (bh, qt>=7) -> y ------------------
__global__ __launch_bounds__(256) void k_combine(const float* __restrict__ pacc,
                                                 const float* __restrict__ pml,
                                                 unsigned short* __restrict__ y) {
    int blk = blockIdx.x;              // 384 = 64 bh x 6 qt
    int bh = blk / 6, qi = blk % 6;
    int qt = 7 + qi;
    int b = bh >> 4, hh = bh & 15;
    int p0 = bh * 12 + qi * 2, p1 = p0 + 1;
    int tid = threadIdx.x;
    int row = tid >> 2;                // 0..63
    int c0 = (tid & 3) * 16;

    float m0 = pml[(size_t)p0 * 128 + row * 2],     l0 = pml[(size_t)p0 * 128 + row * 2 + 1];
    float m1 = pml[(size_t)p1 * 128 + row * 2],     l1 = pml[(size_t)p1 * 128 + row * 2 + 1];
    float m  = fmaxf(m0, m1);
    float s0 = __expf(m0 - m), s1 = __expf(m1 - m);
    float inv = 1.0f / (l0 * s0 + l1 * s1);

    int tt = qt * 64 + row;
    if (tt >= T_SEQ) return;
    const float* a0 = pacc + (size_t)p0 * 4096 + row * 64;
    const float* a1 = pacc + (size_t)p1 * 4096 + row * 64;
    unsigned short* yo = y + ((size_t)(b * T_SEQ) + tt) * 1024 + hh * 64;
#pragma unroll
    for (int jj = 0; jj < 16; ++jj) {
        int col = c0 + jj;
        float v = (a0[col] * s0 + a1[col] * s1) * inv;
        yo[col] = f2bf(v);
    }
}

extern "C" void kernel_launch(void* const* d_in, const int* in_sizes, int n_in,
                              void* d_out, int out_size, void* d_ws, size_t ws_size,
                              hipStream_t stream) {
    const float* x   = (const float*)d_in[0];
    const float* h   = (const float*)d_in[1];
    const float* f01 = (const float*)d_in[2];
    const float* f02 = (const float*)d_in[3];
    const float* f12 = (const float*)d_in[4];
    const float* b01 = (const float*)d_in[5];
    const float* b02 = (const float*)d_in[6];
    const float* b12 = (const float*)d_in[7];
    const float* Wq  = (const float*)d_in[8];
    const float* bq  = (const float*)d_in[9];
    const float* Wk  = (const float*)d_in[10];
    const float* bk  = (const float*)d_in[11];
    const float* Wv  = (const float*)d_in[12];
    const float* bv  = (const float*)d_in[13];
    const float* Wp  = (const float*)d_in[14];
    const float* bp  = (const float*)d_in[15];

    char* ws = (char*)d_ws;
    float* pmm    = (float*)(ws + 256);
    float* bl     = (float*)(ws + 256 + 24576);             // 3MB; reused as pml after finalize
    float* cmb    = (float*)(ws + 256 + 24576 + 3145728);
    unsigned short* x_bf  = (unsigned short*)(ws + 256 + 24576 + 3145728 + 4717568);
    unsigned short* WtQKV = x_bf + (size_t)3308 * 1024;
    unsigned short* WtP   = WtQKV + (size_t)3072 * 1024;
    unsigned short* q_bf  = WtP + (size_t)1024 * 1024;
    unsigned short* k_bf  = q_bf + (size_t)64 * T_PAD * 64;
    unsigned short* vTb   = k_bf + (size_t)64 * T_PAD * 64;
    unsigned short* y_bf  = vTb  + (size_t)64 * T_PAD * 64;

    // attn split partials reuse dead regions (x_bf/WtQKV dead after QKV GEMM; bl dead after finalize)
    float* pacc = (float*)x_bf;       // 768 * 4096 * 4B = 12.58 MB <= 13.06 MB (x_bf+WtQKV)
    float* pml  = bl;                 // 768 * 128 * 4B = 393 KB <= 3 MB

    k_front<<<11692, 256, 0, stream>>>(x, x_bf, cmb, q_bf, k_bf, vTb,
                                       Wq, Wk, Wv, Wp, WtQKV,
                                       f01, f02, f12, b01, b02, b12, bl, pmm);
    k_gemm_qkv<<<3696, 256, 0, stream>>>(x_bf, WtQKV, bq, bk, bv, q_bf, k_bf, vTb, 3308,
                                         f01, f02, f12, b01, b02, b12, bl, pmm, cmb);
    k_attn<<<1216, 256, 0, stream>>>(q_bf, k_bf, vTb, h, cmb, y_bf, pacc, pml);
    k_combine<<<384, 256, 0, stream>>>(pacc, pml, y_bf);
    k_proj64<<<832, 256, 0, stream>>>(y_bf, WtP, bp, (float*)d_out, 3308);
}

// Round 18
// 133.076 us; speedup vs baseline: 1.0215x; 1.0215x over previous
//
#include <hip/hip_runtime.h>
#include <math.h>

using bfrag8 = __attribute__((ext_vector_type(8))) short;
using facc4  = __attribute__((ext_vector_type(4))) float;

#define MFMA16(a,b,c) __builtin_amdgcn_mfma_f32_16x16x32_bf16((a),(b),(c),0,0,0)

#define T_SEQ 827
#define T_PAD 832
#define NHEAD 16
#define NEG_INF (-__builtin_inff())
#define CM_TOT 1179392   // 4*542*544

static __device__ __forceinline__ unsigned short f2bf(float f) {
    unsigned int x = __float_as_uint(f);
    unsigned int r = x + 0x7FFFu + ((x >> 16) & 1u);
    return (unsigned short)(r >> 16);
}

// global -> LDS async copy, 16B per lane. LDS dest must be wave-uniform base (+lane*16 auto).
static __device__ __forceinline__ void gl16(const void* g, void* l) {
    __builtin_amdgcn_global_load_lds(
        (const __attribute__((address_space(1))) unsigned int*)g,
        (__attribute__((address_space(3))) unsigned int*)l,
        16, 0, 0);
}

// ---------------- fused front: x->bf16 | cm:=1 | qkv pads | W transpose | blur ----
__global__ __launch_bounds__(256) void k_front(const float* __restrict__ x,
                                               unsigned short* __restrict__ x_bf,
                                               float* __restrict__ cm,
                                               unsigned short* q, unsigned short* k,
                                               unsigned short* vT,
                                               const float* __restrict__ Wq,
                                               const float* __restrict__ Wk,
                                               const float* __restrict__ Wv,
                                               const float* __restrict__ Wp,
                                               unsigned short* __restrict__ Wt_out,
                                               const float* f01, const float* f02, const float* f12,
                                               const float* b01, const float* b02, const float* b12,
                                               float* __restrict__ bl,
                                               float* __restrict__ pmm) {
    __shared__ float tile[32][33];
    __shared__ float img[16][17], tmp[16][17];
    __shared__ float smn[4], smx[4];
    int bid = blockIdx.x, tid = threadIdx.x;

    if (bid < 3308) {
        int i = (bid * 256 + tid) * 4;
        float4 v = *reinterpret_cast<const float4*>(x + i);
        ushort4 o;
        o.x = f2bf(v.x); o.y = f2bf(v.y); o.z = f2bf(v.z); o.w = f2bf(v.w);
        *reinterpret_cast<ushort4*>(x_bf + i) = o;
    } else if (bid < 4460) {
        int base = (bid - 3308) * 1024 + tid * 4;
        if (base + 4 <= CM_TOT) {
            float4 one = {1.f, 1.f, 1.f, 1.f};
            *reinterpret_cast<float4*>(cm + base) = one;
        } else {
#pragma unroll
            for (int j = 0; j < 4; ++j)
                if (base + j < CM_TOT) cm[base + j] = 1.f;
        }
    } else if (bid < 4524) {
        int bh = bid - 4460;
        for (int i = tid; i < 320; i += 256) {
            int t = 827 + i / 64, d = i % 64;
            q[((size_t)bh * T_PAD + t) * 64 + d] = 0;
            k[((size_t)bh * T_PAD + t) * 64 + d] = 0;
        }
        for (int i = tid; i < 4096; i += 256) {
            int d = i >> 6, s = 768 + (i & 63);
            vT[((size_t)bh * 64 + d) * T_PAD + s] = 0;
        }
    } else if (bid < 8620) {
        int i = bid - 4524;
        int z = i >> 10, rem = i & 1023;
        int bx = rem & 31, by = rem >> 5;
        const float* W = (z == 0) ? Wq : (z == 1) ? Wk : (z == 2) ? Wv : Wp;
        unsigned short* Wt = Wt_out + (size_t)z * 1048576;
        int tx = tid & 31, ty0 = tid >> 5;
#pragma unroll
        for (int j = 0; j < 4; ++j) {
            int ty = ty0 + j * 8;
            tile[ty][tx] = W[(size_t)(by * 32 + ty) * 1024 + bx * 32 + tx];
        }
        __syncthreads();
#pragma unroll
        for (int j = 0; j < 4; ++j) {
            int ty = ty0 + j * 8;
            Wt[(size_t)(bx * 32 + ty) * 1024 + by * 32 + tx] = f2bf(tile[tx][ty]);
        }
    } else {
        int i = bid - 8620;
        int m = i >> 10, rem = i & 1023, b = rem >> 8, r = rem & 255;
        const float* f  = (m == 0) ? f01 : (m == 1) ? f02 : f12;
        const float* bm = (m == 0) ? b01 : (m == 1) ? b02 : b12;
        int ii = tid >> 4, j = tid & 15;

        float k1[7]; float ks = 0.f;
#pragma unroll
        for (int d = 0; d < 7; ++d) { float hx = (float)d - 3.f; k1[d] = expf(-0.5f * hx * hx / 2.25f); ks += k1[d]; }
#pragma unroll
        for (int d = 0; d < 7; ++d) k1[d] /= ks;

        size_t idx = (size_t)b * 65536 + (size_t)r * 256 + tid;
        float bi = f[idx] * bm[(size_t)b * 65536 + (size_t)tid * 256 + r];
        img[ii][j] = bi;
        __syncthreads();
        float ha = 0.f;
#pragma unroll
        for (int d = 0; d < 7; ++d) { int p = j - 3 + d; p = p < 0 ? -p : (p > 15 ? 30 - p : p); ha += k1[d] * img[ii][p]; }
        tmp[ii][j] = ha;
        __syncthreads();
        float v = 0.f;
#pragma unroll
        for (int d = 0; d < 7; ++d) { int p = ii - 3 + d; p = p < 0 ? -p : (p > 15 ? 30 - p : p); v += k1[d] * tmp[p][j]; }
        bl[(size_t)m * 262144 + idx] = v;

        float mn = v, mx = v;
#pragma unroll
        for (int off = 32; off; off >>= 1) { mn = fminf(mn, __shfl_xor(mn, off)); mx = fmaxf(mx, __shfl_xor(mx, off)); }
        int wid = tid >> 6, lane = tid & 63;
        if (lane == 0) { smn[wid] = mn; smx[wid] = mx; }
        __syncthreads();
        if (tid == 0) {
            mn = fminf(fminf(smn[0], smn[1]), fminf(smn[2], smn[3]));
            mx = fmaxf(fmaxf(smx[0], smx[1]), fmaxf(smx[2], smx[3]));
            pmm[2 * i]     = mn;    // plain stores, no atomics
            pmm[2 * i + 1] = mx;
        }
    }
}

// ---------------- QKV GEMM 128x128, dbuf LDS + counted vmcnt + finalize tail ------
__global__ __launch_bounds__(256) void k_gemm_qkv(const unsigned short* __restrict__ A,
                                              const unsigned short* __restrict__ Bt,
                                              const float* __restrict__ b0, const float* __restrict__ b1,
                                              const float* __restrict__ b2,
                                              unsigned short* __restrict__ qo, unsigned short* __restrict__ ko,
                                              unsigned short* __restrict__ vo, int M,
                                              const float* f01, const float* f02, const float* f12,
                                              const float* b01, const float* b02, const float* b12,
                                              const float* __restrict__ bl,
                                              const float* __restrict__ pmm,
                                              float* __restrict__ cm) {
    __shared__ unsigned short As[2][4096];
    __shared__ unsigned short Bs[2][4096];
    int bid = blockIdx.x, tid = threadIdx.x;

    if (bid >= 624) {
        int i = bid - 624;
        int m = i >> 10, rem = i & 1023, b = rem >> 8, r = rem & 255;
        float mn = __builtin_inff(), mx = 0.f;
        for (int kk = tid; kk < 1024; kk += 256) {
            int e = m * 1024 + kk;
            mn = fminf(mn, pmm[2 * e]);
            mx = fmaxf(mx, pmm[2 * e + 1]);
        }
#pragma unroll
        for (int off = 32; off; off >>= 1) { mn = fminf(mn, __shfl_xor(mn, off)); mx = fmaxf(mx, __shfl_xor(mx, off)); }
        float* fs = reinterpret_cast<float*>(&As[0][0]);
        int wid = tid >> 6, lane = tid & 63;
        if (lane == 0) { fs[wid] = mn; fs[4 + wid] = mx; }
        __syncthreads();
        mn = fminf(fminf(fs[0], fs[1]), fminf(fs[2], fs[3]));
        mx = fmaxf(fmaxf(fs[4], fs[5]), fmaxf(fs[6], fs[7]));

        const float* f  = (m == 0) ? f01 : (m == 1) ? f02 : f12;
        const float* bm = (m == 0) ? b01 : (m == 1) ? b02 : b12;
        size_t idx = (size_t)b * 65536 + (size_t)r * 256 + tid;
        float w = (bl[(size_t)m * 262144 + idx] - mn) / (mx - mn);
        w = fminf(fmaxf(w, 0.f), 1.f);
        float val = w * f[idx] * bm[(size_t)b * 65536 + (size_t)tid * 256 + r];
        int row = (m == 0) ? r : r + 286;
        int col = (m == 2) ? tid + 286 : tid;
        cm[((size_t)b * 542 + row) * 544 + col] = val;
        return;
    }

    int swz = (bid & 7) * 78 + (bid >> 3);   // 624 = 8*78
    int m0 = (swz % 26) * 128, n0 = (swz / 26) * 128;
    int wid = tid >> 6, lane = tid & 63;
    int g = lane >> 4, l15 = lane & 15;
    int wm = wid >> 1, wn = wid & 1;
    facc4 acc[4][4] = {};

    int ar0 = m0 + (tid >> 2); if (ar0 > M - 1) ar0 = M - 1;
    int ar1 = m0 + 64 + (tid >> 2); if (ar1 > M - 1) ar1 = M - 1;
    const unsigned short* Ap0 = A + (size_t)ar0 * 1024 + (tid & 3) * 8;
    const unsigned short* Ap1 = A + (size_t)ar1 * 1024 + (tid & 3) * 8;
    const unsigned short* Bp0 = Bt + (size_t)(n0 + (tid >> 2)) * 1024 + (tid & 3) * 8;
    const unsigned short* Bp1 = Bp0 + (size_t)64 * 1024;

    auto stage = [&](int koff, int buf) {
        gl16(Ap0 + koff, &As[buf][0] + (wid << 9));
        gl16(Ap1 + koff, &As[buf][0] + (wid << 9) + 2048);
        gl16(Bp0 + koff, &Bs[buf][0] + (wid << 9));
        gl16(Bp1 + koff, &Bs[buf][0] + (wid << 9) + 2048);
    };

    stage(0, 0);
    for (int k0 = 0; k0 < 32; ++k0) {
        int cur = k0 & 1;
        bool morek = (k0 + 1 < 32);
        if (morek) {
            stage((k0 + 1) * 32, cur ^ 1);
            asm volatile("s_waitcnt vmcnt(4)" ::: "memory");
        } else {
            asm volatile("s_waitcnt vmcnt(0)" ::: "memory");
        }
        __builtin_amdgcn_s_barrier();
        __builtin_amdgcn_sched_barrier(0);

        bfrag8 af[4], bf[4];
#pragma unroll
        for (int mi = 0; mi < 4; ++mi)
            af[mi] = *reinterpret_cast<const bfrag8*>(&As[cur][(wm * 64 + mi * 16 + l15) * 32 + g * 8]);
#pragma unroll
        for (int ni = 0; ni < 4; ++ni)
            bf[ni] = *reinterpret_cast<const bfrag8*>(&Bs[cur][(wn * 64 + ni * 16 + l15) * 32 + g * 8]);
        __builtin_amdgcn_s_setprio(1);
#pragma unroll
        for (int mi = 0; mi < 4; ++mi)
#pragma unroll
            for (int ni = 0; ni < 4; ++ni)
                acc[mi][ni] = MFMA16(af[mi], bf[ni], acc[mi][ni]);
        __builtin_amdgcn_s_setprio(0);

        __builtin_amdgcn_sched_barrier(0);
        if (morek) __builtin_amdgcn_s_barrier();
    }

    int which = n0 >> 10;
    const float* bb = (which == 0 ? b0 : (which == 1 ? b1 : b2));
#pragma unroll
    for (int mi = 0; mi < 4; ++mi)
#pragma unroll
        for (int ni = 0; ni < 4; ++ni)
#pragma unroll
            for (int r = 0; r < 4; ++r) {
                int row = m0 + wm * 64 + mi * 16 + g * 4 + r;
                if (row >= M) continue;
                int col = n0 + wn * 64 + ni * 16 + l15;
                float v = acc[mi][ni][r] + bb[col & 1023];
                int b = row / T_SEQ, t = row - b * T_SEQ;
                int cc = col & 1023;
                int hh = cc >> 6, d = cc & 63;
                size_t bh = (size_t)(b * NHEAD + hh);
                if (which == 0) {
                    qo[(bh * T_PAD + t) * 64 + d] = f2bf(v);
                } else if (which == 1) {
                    int du = (((d >> 3) ^ (t & 7)) << 3) | (d & 7);
                    ko[(bh * T_PAD + t) * 64 + du] = f2bf(v);
                } else {
                    int sl = t & 63;
                    int su = (((sl >> 3) ^ (d & 7)) << 3) | (t & 7);
                    vo[(bh * 64 + d) * T_PAD + (t - sl) + su] = f2bf(v);
                }
            }
}

// ---------------- proj GEMM: 64x64 tile, 832 blocks = 3.25/CU ---------------------
__global__ __launch_bounds__(256) void k_proj64(const unsigned short* __restrict__ A,
                                                const unsigned short* __restrict__ Bt,
                                                const float* __restrict__ bias,
                                                float* __restrict__ out, int M) {
    __shared__ unsigned short As[2048];
    __shared__ unsigned short Bs[2048];
    int bid = blockIdx.x, tid = threadIdx.x;
    int swz = (bid & 7) * 104 + (bid >> 3);
    int m0 = (swz % 52) * 64, n0 = (swz / 52) * 64;
    int wid = tid >> 6, lane = tid & 63;
    int g = lane >> 4, l15 = lane & 15;
    int wm = wid >> 1, wn = wid & 1;
    facc4 acc[2][2] = {};

    int ar = m0 + (tid >> 2); if (ar > M - 1) ar = M - 1;
    const unsigned short* Ap = A + (size_t)ar * 1024 + (tid & 3) * 8;
    const unsigned short* Bp = Bt + (size_t)(n0 + (tid >> 2)) * 1024 + (tid & 3) * 8;
    unsigned short* asw = As + (wid << 9);
    unsigned short* bsw = Bs + (wid << 9);

    for (int k0 = 0; k0 < 1024; k0 += 32) {
        if (k0) __syncthreads();
        gl16(Ap + k0, asw);
        gl16(Bp + k0, bsw);
        __syncthreads();
        bfrag8 af[2], bf[2];
#pragma unroll
        for (int mi = 0; mi < 2; ++mi)
            af[mi] = *reinterpret_cast<const bfrag8*>(&As[(wm * 32 + mi * 16 + l15) * 32 + g * 8]);
#pragma unroll
        for (int ni = 0; ni < 2; ++ni)
            bf[ni] = *reinterpret_cast<const bfrag8*>(&Bs[(wn * 32 + ni * 16 + l15) * 32 + g * 8]);
#pragma unroll
        for (int mi = 0; mi < 2; ++mi)
#pragma unroll
            for (int ni = 0; ni < 2; ++ni)
                acc[mi][ni] = MFMA16(af[mi], bf[ni], acc[mi][ni]);
    }

#pragma unroll
    for (int mi = 0; mi < 2; ++mi)
#pragma unroll
        for (int ni = 0; ni < 2; ++ni)
#pragma unroll
            for (int r = 0; r < 4; ++r) {
                int row = m0 + wm * 32 + mi * 16 + g * 4 + r;
                if (row >= M) continue;
                int col = n0 + wn * 32 + ni * 16 + l15;
                out[(size_t)row * 1024 + col] = acc[mi][ni][r] + bias[col];
            }
}

// ---------------- flash attention (best form): swapped QK^T, defer-max, XCD swizzle
__global__ __launch_bounds__(256) void k_attn(const unsigned short* __restrict__ qb,
                                              const unsigned short* __restrict__ kb,
                                              const unsigned short* __restrict__ vT,
                                              const float* __restrict__ h,
                                              const float* __restrict__ cm,
                                              unsigned short* __restrict__ y) {
    int blk0 = blockIdx.x;
    int blk = (blk0 & 7) * 104 + (blk0 >> 3);   // 832 = 8*104, bijective XCD chunks
    int bh = blk / 13;
    int qt = 12 - (blk % 13);       // long blocks first within each bh
    int b = bh >> 4, hh = bh & 15;
    int tid = threadIdx.x, wid = tid >> 6, lane = tid & 63;
    int g = lane >> 4, l15 = lane & 15;
    int t0 = qt * 64 + wid * 16;
    int t = t0 + l15;               // this lane's t-column
    int tcl = t > 826 ? 826 : t;
    int ntiles = qt + 1;

    __shared__ unsigned short Ks[2][4096];
    __shared__ unsigned short Vs[2][4096];
    __shared__ unsigned short Ps[4][1024];
    unsigned short* pw = &Ps[wid][0];

    const unsigned short* Kbase = kb + (size_t)bh * T_PAD * 64;
    const unsigned short* Vbase = vT + (size_t)bh * 64 * T_PAD;
    const float* hrow = h + (size_t)bh * T_SEQ * T_SEQ + (size_t)tcl * T_SEQ;
    int rt = t - 285; rt = rt < 0 ? 0 : (rt > 541 ? 541 : rt);
    const float* cmrow = cm + ((size_t)b * 542 + rt) * 544;
    bool tm = (t >= 285);

    // Q fragments (B-operand; lane l15 = t-column)
    size_t qrow = ((size_t)bh * T_PAD + t) * 64 + g * 8;
    bfrag8 aq0 = *reinterpret_cast<const bfrag8*>(qb + qrow);
    bfrag8 aq1 = *reinterpret_cast<const bfrag8*>(qb + qrow + 32);

    auto stage = [&](int s0, int buf) {
        const unsigned short* kt = Kbase + (size_t)s0 * 64;
        unsigned short* kd = &Ks[buf][0] + (wid << 9);
        gl16(kt + tid * 8, kd);
        gl16(kt + 2048 + tid * 8, kd + 2048);
        const unsigned short* vt = Vbase + s0;
        unsigned short* vd = &Vs[buf][0] + (wid << 9);
        gl16(vt + (size_t)(tid >> 3) * T_PAD + (tid & 7) * 8, vd);
        gl16(vt + (size_t)((tid >> 3) + 32) * T_PAD + (tid & 7) * 8, vd + 2048);
    };

    auto loadh = [&](int s0t, float* hv, float* mv) {
#pragma unroll
        for (int nt = 0; nt < 4; ++nt) {
            int sb = s0t + nt * 16 + 4 * g;
            float h4[4];
            if (sb + 3 <= tcl) {
                __builtin_memcpy(h4, hrow + sb, 16);
            } else {
#pragma unroll
                for (int j = 0; j < 4; ++j) {
                    float hx = 0.f;
                    if (sb + j <= tcl) hx = hrow[sb + j];
                    h4[j] = hx;
                }
            }
            float m4[4];
            if (tm && sb <= 540) {
                __builtin_memcpy(m4, cmrow + sb, 16);
            } else {
#pragma unroll
                for (int j = 0; j < 4; ++j) m4[j] = 1.f;
            }
#pragma unroll
            for (int j = 0; j < 4; ++j) { hv[nt * 4 + j] = h4[j]; mv[nt * 4 + j] = m4[j]; }
        }
    };

    float m_r = NEG_INF, l_r = 0.f;
    facc4 acc[4] = {};
    float hv[16], mv[16];
    loadh(0, hv, mv);
    stage(0, 0);

    for (int it = 0; it < ntiles; ++it) {
        int cur = it & 1, s0 = it * 64;
        bool more = (it + 1 < ntiles);
        bool diag = !more;                 // last tile contains the diagonal
        __syncthreads();                   // stage(it) complete
        if (more) stage(s0 + 64, cur ^ 1);

        // ---- QK^T (swapped: A=K, B=Q) -> lane holds S[s=s0+nt*16+4g+r][t] ----
        facc4 sf[4] = {};
        __builtin_amdgcn_s_setprio(1);
#pragma unroll
        for (int nt = 0; nt < 4; ++nt) {
            int row = nt * 16 + l15;
            const unsigned short* kp = &Ks[cur][row * 64];
            bfrag8 k0 = *reinterpret_cast<const bfrag8*>(kp + ((g ^ (row & 7)) << 3));
            bfrag8 k1 = *reinterpret_cast<const bfrag8*>(kp + (((4 + g) ^ (row & 7)) << 3));
            sf[nt] = MFMA16(k0, aq0, sf[nt]);
            sf[nt] = MFMA16(k1, aq1, sf[nt]);
        }
        __builtin_amdgcn_s_setprio(0);

        // ---- score + in-register partial max ----
        float vmax = NEG_INF;
#pragma unroll
        for (int nt = 0; nt < 4; ++nt)
#pragma unroll
            for (int r = 0; r < 4; ++r) {
                float val = fmaf(sf[nt][r], 0.125f, hv[nt * 4 + r]) * mv[nt * 4 + r];
                if (diag) {
                    int s = s0 + nt * 16 + 4 * g + r;
                    val = (s <= tcl) ? val : NEG_INF;
                }
                sf[nt][r] = val;
                vmax = fmaxf(vmax, val);
            }

        if (more) loadh(s0 + 64, hv, mv);  // prefetch next tile's h/mask

        vmax = fmaxf(vmax, __shfl_xor(vmax, 16));
        vmax = fmaxf(vmax, __shfl_xor(vmax, 32));

        // ---- defer-max (T13): skip rescale when growth <= THR ----
        bool noresc = __all(vmax <= m_r + 6.0f);
        float mnew = fmaxf(m_r, vmax);
        float mexp = noresc ? m_r : mnew;

        float ps = 0.f;
#pragma unroll
        for (int nt = 0; nt < 4; ++nt)
#pragma unroll
            for (int r = 0; r < 4; ++r) {
                float p = __expf(sf[nt][r] - mexp);
                sf[nt][r] = p;
                ps += p;
            }
        ps += __shfl_xor(ps, 16);
        ps += __shfl_xor(ps, 32);

        // ---- pack P (bf16) -> LDS [t][s] swizzled ----
#pragma unroll
        for (int nt = 0; nt < 4; ++nt) {
            unsigned u0, u1;
            asm("v_cvt_pk_bf16_f32 %0, %1, %2" : "=v"(u0) : "v"(sf[nt][0]), "v"(sf[nt][1]));
            asm("v_cvt_pk_bf16_f32 %0, %1, %2" : "=v"(u1) : "v"(sf[nt][2]), "v"(sf[nt][3]));
            int el = (l15 * 64 + nt * 16 + 4 * g) ^ ((l15 & 7) << 3);
            uint2 uu; uu.x = u0; uu.y = u1;
            *reinterpret_cast<uint2*>(&pw[el]) = uu;
        }

        // ---- online-softmax state update ----
        if (!noresc) {
            float scale = __expf(m_r - mnew);
            l_r = l_r * scale + ps;
#pragma unroll
            for (int r = 0; r < 4; ++r) {
                float sc = __int_as_float(__builtin_amdgcn_ds_bpermute((4 * g + r) * 4, __float_as_int(scale)));
#pragma unroll
                for (int dt = 0; dt < 4; ++dt) acc[dt][r] *= sc;
            }
            m_r = mnew;
        } else {
            l_r += ps;
        }

        // ---- PV: A=P (LDS), B=V^T (LDS) ----
        __builtin_amdgcn_s_setprio(1);
#pragma unroll
        for (int c2 = 0; c2 < 2; ++c2) {
            int ela = (l15 * 64 + c2 * 32 + 8 * g) ^ ((l15 & 7) << 3);
            bfrag8 ap = *reinterpret_cast<const bfrag8*>(&pw[ela]);
#pragma unroll
            for (int dt = 0; dt < 4; ++dt) {
                int row = dt * 16 + l15;
                bfrag8 vf = *reinterpret_cast<const bfrag8*>(&Vs[cur][row * 64 + (((c2 * 4 + g) ^ (row & 7)) << 3)]);
                acc[dt] = MFMA16(ap, vf, acc[dt]);
            }
        }
        __builtin_amdgcn_s_setprio(0);
    }

    float linv = 1.0f / l_r;
#pragma unroll
    for (int r = 0; r < 4; ++r) {
        float li = __int_as_float(__builtin_amdgcn_ds_bpermute((4 * g + r) * 4, __float_as_int(linv)));
        int tt = t0 + 4 * g + r;
        if (tt < T_SEQ) {
#pragma unroll
            for (int dt = 0; dt < 4; ++dt)
                y[((size_t)(b * T_SEQ) + tt) * 1024 + hh * 64 + dt * 16 + l15] = f2bf(acc[dt][r] * li);
        }
    }
}

extern "C" void kernel_launch(void* const* d_in, const int* in_sizes, int n_in,
                              void* d_out, int out_size, void* d_ws, size_t ws_size,
                              hipStream_t stream) {
    const float* x   = (const float*)d_in[0];
    const float* h   = (const float*)d_in[1];
    const float* f01 = (const float*)d_in[2];
    const float* f02 = (const float*)d_in[3];
    const float* f12 = (const float*)d_in[4];
    const float* b01 = (const float*)d_in[5];
    const float* b02 = (const float*)d_in[6];
    const float* b12 = (const float*)d_in[7];
    const float* Wq  = (const float*)d_in[8];
    const float* bq  = (const float*)d_in[9];
    const float* Wk  = (const float*)d_in[10];
    const float* bk  = (const float*)d_in[11];
    const float* Wv  = (const float*)d_in[12];
    const float* bv  = (const float*)d_in[13];
    const float* Wp  = (const float*)d_in[14];
    const float* bp  = (const float*)d_in[15];

    char* ws = (char*)d_ws;
    float* pmm    = (float*)(ws + 256);
    float* bl     = (float*)(ws + 256 + 24576);
    float* cmb    = (float*)(ws + 256 + 24576 + 3145728);
    unsigned short* x_bf  = (unsigned short*)(ws + 256 + 24576 + 3145728 + 4717568);
    unsigned short* WtQKV = x_bf + (size_t)3308 * 1024;
    unsigned short* WtP   = WtQKV + (size_t)3072 * 1024;
    unsigned short* q_bf  = WtP + (size_t)1024 * 1024;
    unsigned short* k_bf  = q_bf + (size_t)64 * T_PAD * 64;
    unsigned short* vTb   = k_bf + (size_t)64 * T_PAD * 64;
    unsigned short* y_bf  = vTb  + (size_t)64 * T_PAD * 64;

    k_front<<<11692, 256, 0, stream>>>(x, x_bf, cmb, q_bf, k_bf, vTb,
                                       Wq, Wk, Wv, Wp, WtQKV,
                                       f01, f02, f12, b01, b02, b12, bl, pmm);
    k_gemm_qkv<<<3696, 256, 0, stream>>>(x_bf, WtQKV, bq, bk, bv, q_bf, k_bf, vTb, 3308,
                                         f01, f02, f12, b01, b02, b12, bl, pmm, cmb);
    k_attn<<<832, 256, 0, stream>>>(q_bf, k_bf, vTb, h, cmb, y_bf);
    k_proj64<<<832, 256, 0, stream>>>(y_bf, WtP, bp, (float*)d_out, 3308);
}